// Round 1
// baseline (1312.576 us; speedup 1.0000x reference)
//
#include <hip/hip_runtime.h>

#define HIDDIM 64

// ---------------- GEMM: C[M,64] = A[M,K] @ B[K,64], fp32 ----------------
__global__ __launch_bounds__(256) void gemm64(const float* __restrict__ A,
                                              const float* __restrict__ B,
                                              float* __restrict__ C, int M, int K) {
    const int BK = 16;
    __shared__ float As[64][BK + 1];   // +1 pad: kill bank conflicts on column reads
    __shared__ float Bs[BK][64];
    int tid = threadIdx.x;
    int ty = tid >> 4, tx = tid & 15;  // 16x16 threads, each computes 4x4
    int rowBase = blockIdx.x * 64;
    float acc[4][4] = {};

    for (int k0 = 0; k0 < K; k0 += BK) {
#pragma unroll
        for (int i = 0; i < 4; i++) {           // load A tile: 64 x 16
            int idx = tid + i * 256;
            int r = idx >> 4, c = idx & 15;
            int gr = rowBase + r;
            As[r][c] = (gr < M) ? A[gr * K + k0 + c] : 0.f;
        }
#pragma unroll
        for (int i = 0; i < 4; i++) {           // load B tile: 16 x 64
            int idx = tid + i * 256;
            int r = idx >> 6, c = idx & 63;
            Bs[r][c] = B[(k0 + r) * 64 + c];
        }
        __syncthreads();
#pragma unroll
        for (int kk = 0; kk < BK; ++kk) {
            float a0 = As[ty * 4 + 0][kk];
            float a1 = As[ty * 4 + 1][kk];
            float a2 = As[ty * 4 + 2][kk];
            float a3 = As[ty * 4 + 3][kk];
            float4 b = *reinterpret_cast<const float4*>(&Bs[kk][tx * 4]);
            acc[0][0] += a0 * b.x; acc[0][1] += a0 * b.y; acc[0][2] += a0 * b.z; acc[0][3] += a0 * b.w;
            acc[1][0] += a1 * b.x; acc[1][1] += a1 * b.y; acc[1][2] += a1 * b.z; acc[1][3] += a1 * b.w;
            acc[2][0] += a2 * b.x; acc[2][1] += a2 * b.y; acc[2][2] += a2 * b.z; acc[2][3] += a2 * b.w;
            acc[3][0] += a3 * b.x; acc[3][1] += a3 * b.y; acc[3][2] += a3 * b.z; acc[3][3] += a3 * b.w;
        }
        __syncthreads();
    }
#pragma unroll
    for (int i = 0; i < 4; i++) {
        int gr = rowBase + ty * 4 + i;
        if (gr < M) {
            float4 v = make_float4(acc[i][0], acc[i][1], acc[i][2], acc[i][3]);
            *reinterpret_cast<float4*>(&C[gr * 64 + tx * 4]) = v;
        }
    }
}

// ---------------- per-node attention scores: as = h.a_src, ad = h.a_dst ----------------
__global__ __launch_bounds__(256) void alpha_kernel(const float* __restrict__ h,
                                                    const float* __restrict__ a_src,
                                                    const float* __restrict__ a_dst,
                                                    float* __restrict__ as_,
                                                    float* __restrict__ ad_, int N) {
    int wid = (blockIdx.x * blockDim.x + threadIdx.x) >> 6;
    int lane = threadIdx.x & 63;
    if (wid >= N) return;
    float v = h[wid * 64 + lane];
    float s1 = v * a_src[lane];
    float s2 = v * a_dst[lane];
#pragma unroll
    for (int off = 32; off; off >>= 1) {
        s1 += __shfl_xor(s1, off);
        s2 += __shfl_xor(s2, off);
    }
    if (lane == 0) { as_[wid] = s1; ad_[wid] = s2; }
}

// ---------------- edge scatter: one wave per edge ----------------
// w = exp(leaky_relu(as[s] + ad[d])); den[d] += w; acc[d][:] += w * h[s][:]
__global__ __launch_bounds__(256) void edge_kernel(const float* __restrict__ h,
                                                   const float* __restrict__ as_,
                                                   const float* __restrict__ ad_,
                                                   const int* __restrict__ esrc,
                                                   const int* __restrict__ edst,
                                                   float* __restrict__ acc,
                                                   float* __restrict__ den, int E, int N) {
    int gid = blockIdx.x * blockDim.x + threadIdx.x;
    int e = gid >> 6;
    int lane = threadIdx.x & 63;
    if (e >= E + N) return;
    int s, d;
    if (e < E) { s = esrc[e]; d = edst[e]; }
    else       { s = e - E;   d = s;       }
    float sc = as_[s] + ad_[d];
    sc = sc > 0.f ? sc : 0.2f * sc;          // leaky_relu, slope 0.2
    float wgt = __expf(sc);                  // no max-subtract: |sc| <= ~10, safe in fp32
    if (lane == 0) unsafeAtomicAdd(&den[d], wgt);
    float hv = h[s * 64 + lane];
    unsafeAtomicAdd(&acc[d * 64 + lane], wgt * hv);
}

// ---------------- normalize + bias + relu (in place on acc) ----------------
__global__ __launch_bounds__(256) void finalize_kernel(float* __restrict__ acc,
                                                       const float* __restrict__ den,
                                                       const float* __restrict__ b, int N) {
    int t = blockIdx.x * blockDim.x + threadIdx.x;
    if (t >= N * 64) return;
    int n = t >> 6, c = t & 63;
    float v = acc[t] / den[n] + b[c];
    acc[t] = v > 0.f ? v : 0.f;
}

// ---------------- output heads: factors [N,3], skills [N,7] ----------------
__global__ __launch_bounds__(256) void heads_kernel(const float* __restrict__ h,
                                                    const float* __restrict__ Wf,
                                                    const float* __restrict__ bf,
                                                    const float* __restrict__ Ws,
                                                    const float* __restrict__ bs,
                                                    float* __restrict__ out, int N) {
    int t = blockIdx.x * blockDim.x + threadIdx.x;
    if (t >= N * 16) return;
    int n = t >> 4, j = t & 15;
    if (j >= 10) return;
    const float* hr = h + n * 64;
    if (j < 3) {
        float sum = bf[j];
#pragma unroll 8
        for (int k = 0; k < 64; k++) sum += hr[k] * Wf[k * 3 + j];
        out[n * 3 + j] = sum;
    } else {
        int jj = j - 3;
        float sum = bs[jj];
#pragma unroll 8
        for (int k = 0; k < 64; k++) sum += hr[k] * Ws[k * 7 + jj];
        out[N * 3 + n * 7 + jj] = sum;
    }
}

extern "C" void kernel_launch(void* const* d_in, const int* in_sizes, int n_in,
                              void* d_out, int out_size, void* d_ws, size_t ws_size,
                              hipStream_t stream) {
    const float* x      = (const float*)d_in[0];
    const int*   ei     = (const int*)  d_in[1];
    const float* W1     = (const float*)d_in[2];
    const float* a_src1 = (const float*)d_in[3];
    const float* a_dst1 = (const float*)d_in[4];
    const float* b1     = (const float*)d_in[5];
    const float* W2     = (const float*)d_in[6];
    const float* a_src2 = (const float*)d_in[7];
    const float* a_dst2 = (const float*)d_in[8];
    const float* b2     = (const float*)d_in[9];
    const float* Wf     = (const float*)d_in[10];
    const float* bf     = (const float*)d_in[11];
    const float* Ws     = (const float*)d_in[12];
    const float* bs     = (const float*)d_in[13];
    float* out = (float*)d_out;

    const int IN = 256;
    int N = in_sizes[0] / IN;      // 100000
    int E = in_sizes[1] / 2;       // 1600000

    char* ws = (char*)d_ws;
    float* h   = (float*)ws;  ws += (size_t)N * 64 * sizeof(float);
    float* acc = (float*)ws;  ws += (size_t)N * 64 * sizeof(float);
    float* as_ = (float*)ws;  ws += (size_t)N * sizeof(float);
    float* ad_ = (float*)ws;  ws += (size_t)N * sizeof(float);
    float* den = (float*)ws;  ws += (size_t)N * sizeof(float);

    const int* esrc = ei;
    const int* edst = ei + E;

    int gemmGrid  = (N + 63) / 64;
    int nodeGrid  = (N * 64 + 255) / 256;       // one wave per node (4 waves/block)
    int edgeGrid  = ((E + N) * 64 + 255) / 256; // one wave per edge
    int elemGrid  = (N * 64 + 255) / 256;
    int headGrid  = (N * 16 + 255) / 256;

    // ---- layer 1 ----
    gemm64<<<gemmGrid, 256, 0, stream>>>(x, W1, h, N, IN);
    alpha_kernel<<<nodeGrid, 256, 0, stream>>>(h, a_src1, a_dst1, as_, ad_, N);
    hipMemsetAsync(acc, 0, (size_t)N * 64 * sizeof(float), stream);
    hipMemsetAsync(den, 0, (size_t)N * sizeof(float), stream);
    edge_kernel<<<edgeGrid, 256, 0, stream>>>(h, as_, ad_, esrc, edst, acc, den, E, N);
    finalize_kernel<<<elemGrid, 256, 0, stream>>>(acc, den, b1, N);

    // ---- layer 2 (acc holds layer-1 output) ----
    gemm64<<<gemmGrid, 256, 0, stream>>>(acc, W2, h, N, 64);
    alpha_kernel<<<nodeGrid, 256, 0, stream>>>(h, a_src2, a_dst2, as_, ad_, N);
    hipMemsetAsync(acc, 0, (size_t)N * 64 * sizeof(float), stream);
    hipMemsetAsync(den, 0, (size_t)N * sizeof(float), stream);
    edge_kernel<<<edgeGrid, 256, 0, stream>>>(h, as_, ad_, esrc, edst, acc, den, E, N);
    finalize_kernel<<<elemGrid, 256, 0, stream>>>(acc, den, b2, N);

    // ---- heads ----
    heads_kernel<<<headGrid, 256, 0, stream>>>(acc, Wf, bf, Ws, bs, out, N);
}

// Round 2
// 806.938 us; speedup vs baseline: 1.6266x; 1.6266x over previous
//
#include <hip/hip_runtime.h>

// ================= graph build: CSR by dst =================
__global__ __launch_bounds__(256) void init_deg(int* deg, int N) {
    int i = blockIdx.x * blockDim.x + threadIdx.x;
    if (i < N) deg[i] = 1;                     // self-loop
}

__global__ __launch_bounds__(256) void count_deg(const int* __restrict__ edst,
                                                 int* __restrict__ deg, int E) {
    int e = blockIdx.x * blockDim.x + threadIdx.x;
    if (e < E) atomicAdd(&deg[edst[e]], 1);
}

// 3-pass exclusive scan of deg[N] -> rowstart[N] (1024 elems per block)
__global__ __launch_bounds__(256) void scan_pass1(const int* __restrict__ deg,
                                                  int* __restrict__ partials, int N) {
    __shared__ int sd[256];
    int b = blockIdx.x, t = threadIdx.x;
    int base = b * 1024 + t * 4;
    int s = 0;
#pragma unroll
    for (int k = 0; k < 4; k++) s += (base + k < N) ? deg[base + k] : 0;
    sd[t] = s; __syncthreads();
    for (int off = 1; off < 256; off <<= 1) {
        int v = (t >= off) ? sd[t - off] : 0;
        __syncthreads();
        sd[t] += v;
        __syncthreads();
    }
    if (t == 255) partials[b] = sd[255];
}

__global__ __launch_bounds__(256) void scan_pass2(int* __restrict__ partials, int nblk) {
    __shared__ int sd[256];
    int t = threadIdx.x;
    int v[4]; int s = 0;
#pragma unroll
    for (int k = 0; k < 4; k++) { int i = t * 4 + k; v[k] = (i < nblk) ? partials[i] : 0; s += v[k]; }
    sd[t] = s; __syncthreads();
    for (int off = 1; off < 256; off <<= 1) {
        int x = (t >= off) ? sd[t - off] : 0;
        __syncthreads();
        sd[t] += x;
        __syncthreads();
    }
    int run = sd[t] - s;    // exclusive
#pragma unroll
    for (int k = 0; k < 4; k++) { int i = t * 4 + k; if (i < nblk) partials[i] = run; run += v[k]; }
}

__global__ __launch_bounds__(256) void scan_pass3(const int* __restrict__ deg,
                                                  const int* __restrict__ partials,
                                                  int* __restrict__ rowstart, int N) {
    __shared__ int sd[256];
    int b = blockIdx.x, t = threadIdx.x;
    int base = b * 1024 + t * 4;
    int v[4]; int s = 0;
#pragma unroll
    for (int k = 0; k < 4; k++) { v[k] = (base + k < N) ? deg[base + k] : 0; s += v[k]; }
    sd[t] = s; __syncthreads();
    for (int off = 1; off < 256; off <<= 1) {
        int x = (t >= off) ? sd[t - off] : 0;
        __syncthreads();
        sd[t] += x;
        __syncthreads();
    }
    int run = partials[b] + sd[t] - s;
#pragma unroll
    for (int k = 0; k < 4; k++) { if (base + k < N) rowstart[base + k] = run; run += v[k]; }
}

__global__ __launch_bounds__(256) void scatter_kernel(const int* __restrict__ esrc,
                                                      const int* __restrict__ edst,
                                                      int* __restrict__ cursor,
                                                      int* __restrict__ sorted_src, int E, int N) {
    int e = blockIdx.x * blockDim.x + threadIdx.x;
    if (e >= E + N) return;
    int s, d;
    if (e < E) { s = esrc[e]; d = edst[e]; }
    else       { s = e - E;   d = s;       }
    int pos = atomicAdd(&cursor[d], 1);
    sorted_src[pos] = s;
}

// ================= GEMM: C[M,64] = A[M,K] @ B[K,64], fp32 =================
__global__ __launch_bounds__(256) void gemm64(const float* __restrict__ A,
                                              const float* __restrict__ B,
                                              float* __restrict__ C, int M, int K) {
    const int BK = 16;
    __shared__ float As[64][BK + 1];
    __shared__ float Bs[BK][64];
    int tid = threadIdx.x;
    int ty = tid >> 4, tx = tid & 15;
    int rowBase = blockIdx.x * 64;
    float acc[4][4] = {};

    for (int k0 = 0; k0 < K; k0 += BK) {
#pragma unroll
        for (int i = 0; i < 4; i++) {
            int idx = tid + i * 256;
            int r = idx >> 4, c = idx & 15;
            int gr = rowBase + r;
            As[r][c] = (gr < M) ? A[gr * K + k0 + c] : 0.f;
        }
#pragma unroll
        for (int i = 0; i < 4; i++) {
            int idx = tid + i * 256;
            int r = idx >> 6, c = idx & 63;
            Bs[r][c] = B[(k0 + r) * 64 + c];
        }
        __syncthreads();
#pragma unroll
        for (int kk = 0; kk < BK; ++kk) {
            float a0 = As[ty * 4 + 0][kk];
            float a1 = As[ty * 4 + 1][kk];
            float a2 = As[ty * 4 + 2][kk];
            float a3 = As[ty * 4 + 3][kk];
            float4 b = *reinterpret_cast<const float4*>(&Bs[kk][tx * 4]);
            acc[0][0] += a0 * b.x; acc[0][1] += a0 * b.y; acc[0][2] += a0 * b.z; acc[0][3] += a0 * b.w;
            acc[1][0] += a1 * b.x; acc[1][1] += a1 * b.y; acc[1][2] += a1 * b.z; acc[1][3] += a1 * b.w;
            acc[2][0] += a2 * b.x; acc[2][1] += a2 * b.y; acc[2][2] += a2 * b.z; acc[2][3] += a2 * b.w;
            acc[3][0] += a3 * b.x; acc[3][1] += a3 * b.y; acc[3][2] += a3 * b.z; acc[3][3] += a3 * b.w;
        }
        __syncthreads();
    }
#pragma unroll
    for (int i = 0; i < 4; i++) {
        int gr = rowBase + ty * 4 + i;
        if (gr < M) {
            float4 v = make_float4(acc[i][0], acc[i][1], acc[i][2], acc[i][3]);
            *reinterpret_cast<float4*>(&C[gr * 64 + tx * 4]) = v;
        }
    }
}

// ================= per-node attention scores =================
__global__ __launch_bounds__(256) void alpha_kernel(const float* __restrict__ h,
                                                    const float* __restrict__ a_src,
                                                    const float* __restrict__ a_dst,
                                                    float* __restrict__ as_,
                                                    float* __restrict__ ad_, int N) {
    int wid = (blockIdx.x * blockDim.x + threadIdx.x) >> 6;
    int lane = threadIdx.x & 63;
    if (wid >= N) return;
    float v = h[wid * 64 + lane];
    float s1 = v * a_src[lane];
    float s2 = v * a_dst[lane];
#pragma unroll
    for (int off = 32; off; off >>= 1) {
        s1 += __shfl_xor(s1, off);
        s2 += __shfl_xor(s2, off);
    }
    if (lane == 0) { as_[wid] = s1; ad_[wid] = s2; }
}

// ================= gather aggregation: one wave per dst node =================
__global__ __launch_bounds__(256) void aggregate_kernel(const float* __restrict__ h,
                                                        const float* __restrict__ as_,
                                                        const float* __restrict__ ad_,
                                                        const int* __restrict__ rowstart,
                                                        const int* __restrict__ sorted_src,
                                                        const float* __restrict__ bias,
                                                        float* __restrict__ outp,
                                                        int N, int total) {
    int wid = (blockIdx.x * blockDim.x + threadIdx.x) >> 6;
    int lane = threadIdx.x & 63;
    if (wid >= N) return;
    int beg = rowstart[wid];
    int end = (wid + 1 < N) ? rowstart[wid + 1] : total;
    float a_d = ad_[wid];
    float acc = 0.f, den = 0.f;
    int j = beg;
    for (; j + 1 < end; j += 2) {                 // 2-way unroll: 2 gathers in flight
        int s0 = sorted_src[j], s1 = sorted_src[j + 1];
        float e0 = as_[s0] + a_d, e1 = as_[s1] + a_d;
        e0 = e0 > 0.f ? e0 : 0.2f * e0;
        e1 = e1 > 0.f ? e1 : 0.2f * e1;
        float w0 = __expf(e0), w1 = __expf(e1);
        float h0 = h[(size_t)s0 * 64 + lane];
        float h1 = h[(size_t)s1 * 64 + lane];
        den += w0 + w1;
        acc += w0 * h0 + w1 * h1;
    }
    if (j < end) {
        int s0 = sorted_src[j];
        float e0 = as_[s0] + a_d;
        e0 = e0 > 0.f ? e0 : 0.2f * e0;
        float w0 = __expf(e0);
        den += w0;
        acc += w0 * h[(size_t)s0 * 64 + lane];
    }
    float v = acc / den + bias[lane];
    outp[(size_t)wid * 64 + lane] = v > 0.f ? v : 0.f;
}

// ================= output heads =================
__global__ __launch_bounds__(256) void heads_kernel(const float* __restrict__ h,
                                                    const float* __restrict__ Wf,
                                                    const float* __restrict__ bf,
                                                    const float* __restrict__ Ws,
                                                    const float* __restrict__ bs,
                                                    float* __restrict__ out, int N) {
    int t = blockIdx.x * blockDim.x + threadIdx.x;
    if (t >= N * 16) return;
    int n = t >> 4, j = t & 15;
    if (j >= 10) return;
    const float* hr = h + (size_t)n * 64;
    if (j < 3) {
        float sum = bf[j];
#pragma unroll 8
        for (int k = 0; k < 64; k++) sum += hr[k] * Wf[k * 3 + j];
        out[(size_t)n * 3 + j] = sum;
    } else {
        int jj = j - 3;
        float sum = bs[jj];
#pragma unroll 8
        for (int k = 0; k < 64; k++) sum += hr[k] * Ws[k * 7 + jj];
        out[(size_t)N * 3 + (size_t)n * 7 + jj] = sum;
    }
}

extern "C" void kernel_launch(void* const* d_in, const int* in_sizes, int n_in,
                              void* d_out, int out_size, void* d_ws, size_t ws_size,
                              hipStream_t stream) {
    const float* x      = (const float*)d_in[0];
    const int*   ei     = (const int*)  d_in[1];
    const float* W1     = (const float*)d_in[2];
    const float* a_src1 = (const float*)d_in[3];
    const float* a_dst1 = (const float*)d_in[4];
    const float* b1     = (const float*)d_in[5];
    const float* W2     = (const float*)d_in[6];
    const float* a_src2 = (const float*)d_in[7];
    const float* a_dst2 = (const float*)d_in[8];
    const float* b2     = (const float*)d_in[9];
    const float* Wf     = (const float*)d_in[10];
    const float* bf     = (const float*)d_in[11];
    const float* Ws     = (const float*)d_in[12];
    const float* bs     = (const float*)d_in[13];
    float* out = (float*)d_out;

    const int IN = 256;
    int N = in_sizes[0] / IN;      // 100000
    int E = in_sizes[1] / 2;       // 1600000
    int total = E + N;

    char* ws = (char*)d_ws;
    float* h        = (float*)ws;  ws += (size_t)N * 64 * sizeof(float);
    float* g        = (float*)ws;  ws += (size_t)N * 64 * sizeof(float);
    float* as_      = (float*)ws;  ws += (size_t)N * sizeof(float);
    float* ad_      = (float*)ws;  ws += (size_t)N * sizeof(float);
    int* rowstart   = (int*)ws;    ws += (size_t)(N + 1) * sizeof(int);
    int* cursor     = (int*)ws;    ws += (size_t)N * sizeof(int);   // also used as deg
    int* sorted_src = (int*)ws;    ws += (size_t)total * sizeof(int);
    int* partials   = (int*)ws;    ws += 1024 * sizeof(int);

    const int* esrc = ei;
    const int* edst = ei + E;

    int nblk = (N + 1023) / 1024;
    int gemmGrid = (N + 63) / 64;
    int nodeGrid = (N * 64 + 255) / 256;
    int aggGrid  = (N * 64 + 255) / 256;
    int headGrid = (N * 16 + 255) / 256;

    // ---- build CSR (once, shared by both layers) ----
    init_deg<<<(N + 255) / 256, 256, 0, stream>>>(cursor, N);
    count_deg<<<(E + 255) / 256, 256, 0, stream>>>(edst, cursor, E);
    scan_pass1<<<nblk, 256, 0, stream>>>(cursor, partials, N);
    scan_pass2<<<1, 256, 0, stream>>>(partials, nblk);
    scan_pass3<<<nblk, 256, 0, stream>>>(cursor, partials, rowstart, N);
    hipMemcpyAsync(cursor, rowstart, (size_t)N * sizeof(int), hipMemcpyDeviceToDevice, stream);
    scatter_kernel<<<(total + 255) / 256, 256, 0, stream>>>(esrc, edst, cursor, sorted_src, E, N);

    // ---- layer 1 ----
    gemm64<<<gemmGrid, 256, 0, stream>>>(x, W1, h, N, IN);
    alpha_kernel<<<nodeGrid, 256, 0, stream>>>(h, a_src1, a_dst1, as_, ad_, N);
    aggregate_kernel<<<aggGrid, 256, 0, stream>>>(h, as_, ad_, rowstart, sorted_src, b1, g, N, total);

    // ---- layer 2 ----
    gemm64<<<gemmGrid, 256, 0, stream>>>(g, W2, h, N, 64);
    alpha_kernel<<<nodeGrid, 256, 0, stream>>>(h, a_src2, a_dst2, as_, ad_, N);
    aggregate_kernel<<<aggGrid, 256, 0, stream>>>(h, as_, ad_, rowstart, sorted_src, b2, g, N, total);

    // ---- heads ----
    heads_kernel<<<headGrid, 256, 0, stream>>>(g, Wf, bf, Ws, bs, out, N);
}

// Round 3
// 783.495 us; speedup vs baseline: 1.6753x; 1.0299x over previous
//
#include <hip/hip_runtime.h>

// ================= graph build: CSR by dst, XCD-region-partitioned =================
__global__ __launch_bounds__(256) void init_deg(int* deg, int N) {
    int i = blockIdx.x * blockDim.x + threadIdx.x;
    if (i < N) deg[i] = 1;                     // self-loop
}

// grid = 256 chunks x 8 regions; block handles only dsts in its region so the
// deg[] atomics stay in one XCD's L2 (blockIdx round-robins XCDs).
__global__ __launch_bounds__(256) void count_deg_r(const int* __restrict__ edst,
                                                   int* __restrict__ deg, int E,
                                                   float inv, int per_chunk) {
    int r = blockIdx.x & 7;
    int chunk = blockIdx.x >> 3;
    int base = chunk * per_chunk;
    int end = min(E, base + per_chunk);
    for (int e = base + (int)threadIdx.x; e < end; e += 256) {
        int d = edst[e];
        int reg = (int)((float)d * inv); reg = reg > 7 ? 7 : reg;
        if (reg == r) atomicAdd(&deg[d], 1);
    }
}

// 3-pass exclusive scan of deg[N] -> rowstart[N]
__global__ __launch_bounds__(256) void scan_pass1(const int* __restrict__ deg,
                                                  int* __restrict__ partials, int N) {
    __shared__ int sd[256];
    int b = blockIdx.x, t = threadIdx.x;
    int base = b * 1024 + t * 4;
    int s = 0;
#pragma unroll
    for (int k = 0; k < 4; k++) s += (base + k < N) ? deg[base + k] : 0;
    sd[t] = s; __syncthreads();
    for (int off = 1; off < 256; off <<= 1) {
        int v = (t >= off) ? sd[t - off] : 0;
        __syncthreads();
        sd[t] += v;
        __syncthreads();
    }
    if (t == 255) partials[b] = sd[255];
}

__global__ __launch_bounds__(256) void scan_pass2(int* __restrict__ partials, int nblk) {
    __shared__ int sd[256];
    int t = threadIdx.x;
    int v[4]; int s = 0;
#pragma unroll
    for (int k = 0; k < 4; k++) { int i = t * 4 + k; v[k] = (i < nblk) ? partials[i] : 0; s += v[k]; }
    sd[t] = s; __syncthreads();
    for (int off = 1; off < 256; off <<= 1) {
        int x = (t >= off) ? sd[t - off] : 0;
        __syncthreads();
        sd[t] += x;
        __syncthreads();
    }
    int run = sd[t] - s;
#pragma unroll
    for (int k = 0; k < 4; k++) { int i = t * 4 + k; if (i < nblk) partials[i] = run; run += v[k]; }
}

__global__ __launch_bounds__(256) void scan_pass3(const int* __restrict__ deg,
                                                  const int* __restrict__ partials,
                                                  int* __restrict__ rowstart, int N) {
    __shared__ int sd[256];
    int b = blockIdx.x, t = threadIdx.x;
    int base = b * 1024 + t * 4;
    int v[4]; int s = 0;
#pragma unroll
    for (int k = 0; k < 4; k++) { v[k] = (base + k < N) ? deg[base + k] : 0; s += v[k]; }
    sd[t] = s; __syncthreads();
    for (int off = 1; off < 256; off <<= 1) {
        int x = (t >= off) ? sd[t - off] : 0;
        __syncthreads();
        sd[t] += x;
        __syncthreads();
    }
    int run = partials[b] + sd[t] - s;
#pragma unroll
    for (int k = 0; k < 4; k++) { if (base + k < N) rowstart[base + k] = run; run += v[k]; }
}

// region-partitioned scatter: writes into one region's CSR slice stay XCD-local
__global__ __launch_bounds__(256) void scatter_r(const int* __restrict__ esrc,
                                                 const int* __restrict__ edst,
                                                 int* __restrict__ cursor,
                                                 int* __restrict__ sorted_src,
                                                 int E, int total, float inv, int per_chunk) {
    int r = blockIdx.x & 7;
    int chunk = blockIdx.x >> 3;
    int base = chunk * per_chunk;
    int end = min(total, base + per_chunk);
    for (int e = base + (int)threadIdx.x; e < end; e += 256) {
        int s, d;
        if (e < E) { s = esrc[e]; d = edst[e]; }
        else       { s = e - E;   d = s;       }
        int reg = (int)((float)d * inv); reg = reg > 7 ? 7 : reg;
        if (reg == r) {
            int pos = atomicAdd(&cursor[d], 1);
            sorted_src[pos] = s;
        }
    }
}

// ================= GEMM: C[M,64] = A[M,K] @ B[K,64], fp32, 256x64 tile, 8x8 micro =================
__global__ __launch_bounds__(256) void gemm64(const float* __restrict__ A,
                                              const float* __restrict__ B,
                                              float* __restrict__ C, int M, int K) {
    const int BK = 16;
    __shared__ float AsT[BK][260];   // transposed, stride 260 -> 2-way (free) bank pattern
    __shared__ float Bs[BK][64];
    int tid = threadIdx.x;
    int tx = tid & 7;                // 8 col-groups * 8 cols
    int ty = tid >> 3;               // 32 row-groups * 8 rows
    int rowBase = blockIdx.x * 256;
    float acc[8][8] = {};

    for (int k0 = 0; k0 < K; k0 += BK) {
#pragma unroll
        for (int i = 0; i < 16; i++) {          // A tile: 256 rows x 16 cols
            int idx = tid + i * 256;
            int r = idx >> 4, c = idx & 15;
            int gr = rowBase + r;
            AsT[c][r] = (gr < M) ? A[(size_t)gr * K + k0 + c] : 0.f;
        }
#pragma unroll
        for (int i = 0; i < 4; i++) {           // B tile: 16 x 64
            int idx = tid + i * 256;
            int r = idx >> 6, c = idx & 63;
            Bs[r][c] = B[(size_t)(k0 + r) * 64 + c];
        }
        __syncthreads();
#pragma unroll
        for (int kk = 0; kk < BK; ++kk) {
            float a[8], b[8];
            *reinterpret_cast<float4*>(&a[0]) = *reinterpret_cast<const float4*>(&AsT[kk][ty * 8]);
            *reinterpret_cast<float4*>(&a[4]) = *reinterpret_cast<const float4*>(&AsT[kk][ty * 8 + 4]);
            *reinterpret_cast<float4*>(&b[0]) = *reinterpret_cast<const float4*>(&Bs[kk][tx * 8]);
            *reinterpret_cast<float4*>(&b[4]) = *reinterpret_cast<const float4*>(&Bs[kk][tx * 8 + 4]);
#pragma unroll
            for (int i = 0; i < 8; i++)
#pragma unroll
                for (int j = 0; j < 8; j++)
                    acc[i][j] += a[i] * b[j];
        }
        __syncthreads();
    }
#pragma unroll
    for (int i = 0; i < 8; i++) {
        int gr = rowBase + ty * 8 + i;
        if (gr < M) {
            *reinterpret_cast<float4*>(&C[(size_t)gr * 64 + tx * 8]) =
                make_float4(acc[i][0], acc[i][1], acc[i][2], acc[i][3]);
            *reinterpret_cast<float4*>(&C[(size_t)gr * 64 + tx * 8 + 4]) =
                make_float4(acc[i][4], acc[i][5], acc[i][6], acc[i][7]);
        }
    }
}

// ================= per-node attention scores =================
__global__ __launch_bounds__(256) void alpha_kernel(const float* __restrict__ h,
                                                    const float* __restrict__ a_src,
                                                    const float* __restrict__ a_dst,
                                                    float* __restrict__ as_,
                                                    float* __restrict__ ad_, int N) {
    int wid = (blockIdx.x * blockDim.x + threadIdx.x) >> 6;
    int lane = threadIdx.x & 63;
    if (wid >= N) return;
    float v = h[(size_t)wid * 64 + lane];
    float s1 = v * a_src[lane];
    float s2 = v * a_dst[lane];
#pragma unroll
    for (int off = 32; off; off >>= 1) {
        s1 += __shfl_xor(s1, off);
        s2 += __shfl_xor(s2, off);
    }
    if (lane == 0) { as_[wid] = s1; ad_[wid] = s2; }
}

// ================= gather aggregation: one wave per dst node =================
__global__ __launch_bounds__(256) void aggregate_kernel(const float* __restrict__ h,
                                                        const float* __restrict__ as_,
                                                        const float* __restrict__ ad_,
                                                        const int* __restrict__ rowstart,
                                                        const int* __restrict__ sorted_src,
                                                        const float* __restrict__ bias,
                                                        float* __restrict__ outp,
                                                        int N, int total) {
    int wid = (blockIdx.x * blockDim.x + threadIdx.x) >> 6;
    int lane = threadIdx.x & 63;
    if (wid >= N) return;
    int beg = rowstart[wid];
    int end = (wid + 1 < N) ? rowstart[wid + 1] : total;
    float a_d = ad_[wid];
    float acc = 0.f, den = 0.f;
    int j = beg;
    for (; j + 3 < end; j += 4) {                 // 4 gathers in flight
        int s0 = sorted_src[j],     s1 = sorted_src[j + 1];
        int s2 = sorted_src[j + 2], s3 = sorted_src[j + 3];
        float e0 = as_[s0] + a_d, e1 = as_[s1] + a_d;
        float e2 = as_[s2] + a_d, e3 = as_[s3] + a_d;
        e0 = e0 > 0.f ? e0 : 0.2f * e0;
        e1 = e1 > 0.f ? e1 : 0.2f * e1;
        e2 = e2 > 0.f ? e2 : 0.2f * e2;
        e3 = e3 > 0.f ? e3 : 0.2f * e3;
        float w0 = __expf(e0), w1 = __expf(e1), w2 = __expf(e2), w3 = __expf(e3);
        float h0 = h[(size_t)s0 * 64 + lane];
        float h1 = h[(size_t)s1 * 64 + lane];
        float h2 = h[(size_t)s2 * 64 + lane];
        float h3 = h[(size_t)s3 * 64 + lane];
        den += (w0 + w1) + (w2 + w3);
        acc += (w0 * h0 + w1 * h1) + (w2 * h2 + w3 * h3);
    }
    for (; j < end; j++) {
        int s0 = sorted_src[j];
        float e0 = as_[s0] + a_d;
        e0 = e0 > 0.f ? e0 : 0.2f * e0;
        float w0 = __expf(e0);
        den += w0;
        acc += w0 * h[(size_t)s0 * 64 + lane];
    }
    float v = acc / den + bias[lane];
    outp[(size_t)wid * 64 + lane] = v > 0.f ? v : 0.f;
}

// ================= output heads =================
__global__ __launch_bounds__(256) void heads_kernel(const float* __restrict__ h,
                                                    const float* __restrict__ Wf,
                                                    const float* __restrict__ bf,
                                                    const float* __restrict__ Ws,
                                                    const float* __restrict__ bs,
                                                    float* __restrict__ out, int N) {
    int t = blockIdx.x * blockDim.x + threadIdx.x;
    if (t >= N * 16) return;
    int n = t >> 4, j = t & 15;
    if (j >= 10) return;
    const float* hr = h + (size_t)n * 64;
    if (j < 3) {
        float sum = bf[j];
#pragma unroll 8
        for (int k = 0; k < 64; k++) sum += hr[k] * Wf[k * 3 + j];
        out[(size_t)n * 3 + j] = sum;
    } else {
        int jj = j - 3;
        float sum = bs[jj];
#pragma unroll 8
        for (int k = 0; k < 64; k++) sum += hr[k] * Ws[k * 7 + jj];
        out[(size_t)N * 3 + (size_t)n * 7 + jj] = sum;
    }
}

extern "C" void kernel_launch(void* const* d_in, const int* in_sizes, int n_in,
                              void* d_out, int out_size, void* d_ws, size_t ws_size,
                              hipStream_t stream) {
    const float* x      = (const float*)d_in[0];
    const int*   ei     = (const int*)  d_in[1];
    const float* W1     = (const float*)d_in[2];
    const float* a_src1 = (const float*)d_in[3];
    const float* a_dst1 = (const float*)d_in[4];
    const float* b1     = (const float*)d_in[5];
    const float* W2     = (const float*)d_in[6];
    const float* a_src2 = (const float*)d_in[7];
    const float* a_dst2 = (const float*)d_in[8];
    const float* b2     = (const float*)d_in[9];
    const float* Wf     = (const float*)d_in[10];
    const float* bf     = (const float*)d_in[11];
    const float* Ws     = (const float*)d_in[12];
    const float* bs     = (const float*)d_in[13];
    float* out = (float*)d_out;

    const int IN = 256;
    int N = in_sizes[0] / IN;      // 100000
    int E = in_sizes[1] / 2;       // 1600000
    int total = E + N;

    char* ws = (char*)d_ws;
    float* h        = (float*)ws;  ws += (size_t)N * 64 * sizeof(float);
    float* g        = (float*)ws;  ws += (size_t)N * 64 * sizeof(float);
    float* as_      = (float*)ws;  ws += (size_t)N * sizeof(float);
    float* ad_      = (float*)ws;  ws += (size_t)N * sizeof(float);
    int* rowstart   = (int*)ws;    ws += (size_t)(N + 1) * sizeof(int);
    int* cursor     = (int*)ws;    ws += (size_t)N * sizeof(int);   // also deg
    int* sorted_src = (int*)ws;    ws += (size_t)total * sizeof(int);
    int* partials   = (int*)ws;    ws += 1024 * sizeof(int);

    const int* esrc = ei;
    const int* edst = ei + E;

    float inv = 8.0f / (float)N;   // dst -> region in [0,8)
    int nblk = (N + 1023) / 1024;
    int gemmGrid = (N + 255) / 256;
    int nodeGrid = (N * 64 + 255) / 256;
    int aggGrid  = (N * 64 + 255) / 256;
    int headGrid = (N * 16 + 255) / 256;
    int pcE = (E + 255) / 256;       // 256 chunks
    int pcT = (total + 255) / 256;

    // ---- build CSR (XCD-region-partitioned atomics/writes) ----
    init_deg<<<(N + 255) / 256, 256, 0, stream>>>(cursor, N);
    count_deg_r<<<2048, 256, 0, stream>>>(edst, cursor, E, inv, pcE);
    scan_pass1<<<nblk, 256, 0, stream>>>(cursor, partials, N);
    scan_pass2<<<1, 256, 0, stream>>>(partials, nblk);
    scan_pass3<<<nblk, 256, 0, stream>>>(cursor, partials, rowstart, N);
    hipMemcpyAsync(cursor, rowstart, (size_t)N * sizeof(int), hipMemcpyDeviceToDevice, stream);
    scatter_r<<<2048, 256, 0, stream>>>(esrc, edst, cursor, sorted_src, E, total, inv, pcT);

    // ---- layer 1 ----
    gemm64<<<gemmGrid, 256, 0, stream>>>(x, W1, h, N, IN);
    alpha_kernel<<<nodeGrid, 256, 0, stream>>>(h, a_src1, a_dst1, as_, ad_, N);
    aggregate_kernel<<<aggGrid, 256, 0, stream>>>(h, as_, ad_, rowstart, sorted_src, b1, g, N, total);

    // ---- layer 2 ----
    gemm64<<<gemmGrid, 256, 0, stream>>>(g, W2, h, N, 64);
    alpha_kernel<<<nodeGrid, 256, 0, stream>>>(h, a_src2, a_dst2, as_, ad_, N);
    aggregate_kernel<<<aggGrid, 256, 0, stream>>>(h, as_, ad_, rowstart, sorted_src, b2, g, N, total);

    // ---- heads ----
    heads_kernel<<<headGrid, 256, 0, stream>>>(g, Wf, bf, Ws, bs, out, N);
}

// Round 4
// 592.367 us; speedup vs baseline: 2.2158x; 1.3227x over previous
//
#include <hip/hip_runtime.h>

// ================= graph build: CSR by dst, XCD-region-partitioned =================
__global__ __launch_bounds__(256) void init_deg(int* deg, int N) {
    int i = blockIdx.x * blockDim.x + threadIdx.x;
    if (i < N) deg[i] = 1;                     // self-loop
}

__global__ __launch_bounds__(256) void count_deg_r(const int* __restrict__ edst,
                                                   int* __restrict__ deg, int E,
                                                   float inv, int per_chunk) {
    int r = blockIdx.x & 7;
    int chunk = blockIdx.x >> 3;
    int base = chunk * per_chunk;
    int end = min(E, base + per_chunk);
    for (int e = base + (int)threadIdx.x; e < end; e += 256) {
        int d = edst[e];
        int reg = (int)((float)d * inv); reg = reg > 7 ? 7 : reg;
        if (reg == r) atomicAdd(&deg[d], 1);
    }
}

__global__ __launch_bounds__(256) void scan_pass1(const int* __restrict__ deg,
                                                  int* __restrict__ partials, int N) {
    __shared__ int sd[256];
    int b = blockIdx.x, t = threadIdx.x;
    int base = b * 1024 + t * 4;
    int s = 0;
#pragma unroll
    for (int k = 0; k < 4; k++) s += (base + k < N) ? deg[base + k] : 0;
    sd[t] = s; __syncthreads();
    for (int off = 1; off < 256; off <<= 1) {
        int v = (t >= off) ? sd[t - off] : 0;
        __syncthreads();
        sd[t] += v;
        __syncthreads();
    }
    if (t == 255) partials[b] = sd[255];
}

__global__ __launch_bounds__(256) void scan_pass2(int* __restrict__ partials, int nblk) {
    __shared__ int sd[256];
    int t = threadIdx.x;
    int v[4]; int s = 0;
#pragma unroll
    for (int k = 0; k < 4; k++) { int i = t * 4 + k; v[k] = (i < nblk) ? partials[i] : 0; s += v[k]; }
    sd[t] = s; __syncthreads();
    for (int off = 1; off < 256; off <<= 1) {
        int x = (t >= off) ? sd[t - off] : 0;
        __syncthreads();
        sd[t] += x;
        __syncthreads();
    }
    int run = sd[t] - s;
#pragma unroll
    for (int k = 0; k < 4; k++) { int i = t * 4 + k; if (i < nblk) partials[i] = run; run += v[k]; }
}

__global__ __launch_bounds__(256) void scan_pass3(const int* __restrict__ deg,
                                                  const int* __restrict__ partials,
                                                  int* __restrict__ rowstart, int N) {
    __shared__ int sd[256];
    int b = blockIdx.x, t = threadIdx.x;
    int base = b * 1024 + t * 4;
    int v[4]; int s = 0;
#pragma unroll
    for (int k = 0; k < 4; k++) { v[k] = (base + k < N) ? deg[base + k] : 0; s += v[k]; }
    sd[t] = s; __syncthreads();
    for (int off = 1; off < 256; off <<= 1) {
        int x = (t >= off) ? sd[t - off] : 0;
        __syncthreads();
        sd[t] += x;
        __syncthreads();
    }
    int run = partials[b] + sd[t] - s;
#pragma unroll
    for (int k = 0; k < 4; k++) { if (base + k < N) rowstart[base + k] = run; run += v[k]; }
}

__global__ __launch_bounds__(256) void scatter_r(const int* __restrict__ esrc,
                                                 const int* __restrict__ edst,
                                                 int* __restrict__ cursor,
                                                 int* __restrict__ sorted_src,
                                                 int E, int total, float inv, int per_chunk) {
    int r = blockIdx.x & 7;
    int chunk = blockIdx.x >> 3;
    int base = chunk * per_chunk;
    int end = min(total, base + per_chunk);
    for (int e = base + (int)threadIdx.x; e < end; e += 256) {
        int s, d;
        if (e < E) { s = esrc[e]; d = edst[e]; }
        else       { s = e - E;   d = s;       }
        int reg = (int)((float)d * inv); reg = reg > 7 ? 7 : reg;
        if (reg == r) {
            int pos = atomicAdd(&cursor[d], 1);
            sorted_src[pos] = s;
        }
    }
}

// ====== GEMM + fused alpha: C[M,64] = A[M,K]@W[K,64]; as_=C.a_src, ad_=C.a_dst ======
// 128x64 tile, 256 threads, 4x8 micro-tile, BK=32.
__global__ __launch_bounds__(256) void gemm_alpha(const float* __restrict__ A,
                                                  const float* __restrict__ W,
                                                  const float* __restrict__ a_src,
                                                  const float* __restrict__ a_dst,
                                                  float* __restrict__ C,
                                                  float* __restrict__ as_,
                                                  float* __restrict__ ad_,
                                                  int M, int K) {
    const int BK = 32;
    __shared__ float AsT[BK][132];   // [k][row] transposed; b128 reads conflict-free
    __shared__ float Bs[BK][64];
    int tid = threadIdx.x;
    int tx = tid & 7;                // col group: cols tx*8 .. tx*8+7
    int ty = tid >> 3;               // row group: rows ty*4 .. ty*4+3
    int rowBase = blockIdx.x * 128;
    float acc[4][8] = {};

    float asv[8], adv[8];
#pragma unroll
    for (int j = 0; j < 8; j++) { asv[j] = a_src[tx * 8 + j]; adv[j] = a_dst[tx * 8 + j]; }

    for (int k0 = 0; k0 < K; k0 += BK) {
        // A tile: 128 rows x 32 k, float4 loads (4 per thread)
#pragma unroll
        for (int i = 0; i < 4; i++) {
            int fidx = 4 * (tid + i * 256);
            int r = fidx >> 5, c = fidx & 31;
            int gr = rowBase + r;
            float4 v = (gr < M) ? *reinterpret_cast<const float4*>(&A[(size_t)gr * K + k0 + c])
                                : make_float4(0.f, 0.f, 0.f, 0.f);
            AsT[c + 0][r] = v.x;
            AsT[c + 1][r] = v.y;
            AsT[c + 2][r] = v.z;
            AsT[c + 3][r] = v.w;
        }
        // B tile: 32 x 64, float4 loads (2 per thread)
#pragma unroll
        for (int i = 0; i < 2; i++) {
            int fidx = 4 * (tid + i * 256);
            int r = fidx >> 6, c = fidx & 63;
            *reinterpret_cast<float4*>(&Bs[r][c]) =
                *reinterpret_cast<const float4*>(&W[(size_t)(k0 + r) * 64 + c]);
        }
        __syncthreads();
#pragma unroll 4
        for (int kk = 0; kk < BK; ++kk) {
            float a[4], b[8];
            *reinterpret_cast<float4*>(&a[0]) = *reinterpret_cast<const float4*>(&AsT[kk][ty * 4]);
            *reinterpret_cast<float4*>(&b[0]) = *reinterpret_cast<const float4*>(&Bs[kk][tx * 8]);
            *reinterpret_cast<float4*>(&b[4]) = *reinterpret_cast<const float4*>(&Bs[kk][tx * 8 + 4]);
#pragma unroll
            for (int i = 0; i < 4; i++)
#pragma unroll
                for (int j = 0; j < 8; j++)
                    acc[i][j] += a[i] * b[j];
        }
        __syncthreads();
    }

#pragma unroll
    for (int i = 0; i < 4; i++) {
        int gr = rowBase + ty * 4 + i;
        // alpha partials over this thread's 8 cols, reduce across the 8 tx lanes
        float s1 = 0.f, s2 = 0.f;
#pragma unroll
        for (int j = 0; j < 8; j++) { s1 += acc[i][j] * asv[j]; s2 += acc[i][j] * adv[j]; }
        s1 += __shfl_xor(s1, 1); s2 += __shfl_xor(s2, 1);
        s1 += __shfl_xor(s1, 2); s2 += __shfl_xor(s2, 2);
        s1 += __shfl_xor(s1, 4); s2 += __shfl_xor(s2, 4);
        if (gr < M) {
            *reinterpret_cast<float4*>(&C[(size_t)gr * 64 + tx * 8]) =
                make_float4(acc[i][0], acc[i][1], acc[i][2], acc[i][3]);
            *reinterpret_cast<float4*>(&C[(size_t)gr * 64 + tx * 8 + 4]) =
                make_float4(acc[i][4], acc[i][5], acc[i][6], acc[i][7]);
            if (tx == 0) { as_[gr] = s1; ad_[gr] = s2; }
        }
    }
}

// ================= gather aggregation: one wave per dst node =================
__global__ __launch_bounds__(256) void aggregate_kernel(const float* __restrict__ h,
                                                        const float* __restrict__ as_,
                                                        const float* __restrict__ ad_,
                                                        const int* __restrict__ rowstart,
                                                        const int* __restrict__ sorted_src,
                                                        const float* __restrict__ bias,
                                                        float* __restrict__ outp,
                                                        int N, int total) {
    int wid = (blockIdx.x * blockDim.x + threadIdx.x) >> 6;
    int lane = threadIdx.x & 63;
    if (wid >= N) return;
    int beg = rowstart[wid];
    int end = (wid + 1 < N) ? rowstart[wid + 1] : total;
    float a_d = ad_[wid];
    float acc = 0.f, den = 0.f;
    int j = beg;
    for (; j + 3 < end; j += 4) {
        int s0 = sorted_src[j],     s1 = sorted_src[j + 1];
        int s2 = sorted_src[j + 2], s3 = sorted_src[j + 3];
        float e0 = as_[s0] + a_d, e1 = as_[s1] + a_d;
        float e2 = as_[s2] + a_d, e3 = as_[s3] + a_d;
        e0 = e0 > 0.f ? e0 : 0.2f * e0;
        e1 = e1 > 0.f ? e1 : 0.2f * e1;
        e2 = e2 > 0.f ? e2 : 0.2f * e2;
        e3 = e3 > 0.f ? e3 : 0.2f * e3;
        float w0 = __expf(e0), w1 = __expf(e1), w2 = __expf(e2), w3 = __expf(e3);
        float h0 = h[(size_t)s0 * 64 + lane];
        float h1 = h[(size_t)s1 * 64 + lane];
        float h2 = h[(size_t)s2 * 64 + lane];
        float h3 = h[(size_t)s3 * 64 + lane];
        den += (w0 + w1) + (w2 + w3);
        acc += (w0 * h0 + w1 * h1) + (w2 * h2 + w3 * h3);
    }
    for (; j < end; j++) {
        int s0 = sorted_src[j];
        float e0 = as_[s0] + a_d;
        e0 = e0 > 0.f ? e0 : 0.2f * e0;
        float w0 = __expf(e0);
        den += w0;
        acc += w0 * h[(size_t)s0 * 64 + lane];
    }
    float v = acc / den + bias[lane];
    outp[(size_t)wid * 64 + lane] = v > 0.f ? v : 0.f;
}

// ====== layer-2 aggregate with fused heads: logits written directly ======
__global__ __launch_bounds__(256) void aggregate_heads(const float* __restrict__ h,
                                                       const float* __restrict__ as_,
                                                       const float* __restrict__ ad_,
                                                       const int* __restrict__ rowstart,
                                                       const int* __restrict__ sorted_src,
                                                       const float* __restrict__ bias,
                                                       const float* __restrict__ Wf,
                                                       const float* __restrict__ bf,
                                                       const float* __restrict__ Ws,
                                                       const float* __restrict__ bs,
                                                       float* __restrict__ out,
                                                       int N, int total) {
    int wid = (blockIdx.x * blockDim.x + threadIdx.x) >> 6;
    int lane = threadIdx.x & 63;
    if (wid >= N) return;
    int beg = rowstart[wid];
    int end = (wid + 1 < N) ? rowstart[wid + 1] : total;
    float a_d = ad_[wid];
    float acc = 0.f, den = 0.f;
    int j = beg;
    for (; j + 3 < end; j += 4) {
        int s0 = sorted_src[j],     s1 = sorted_src[j + 1];
        int s2 = sorted_src[j + 2], s3 = sorted_src[j + 3];
        float e0 = as_[s0] + a_d, e1 = as_[s1] + a_d;
        float e2 = as_[s2] + a_d, e3 = as_[s3] + a_d;
        e0 = e0 > 0.f ? e0 : 0.2f * e0;
        e1 = e1 > 0.f ? e1 : 0.2f * e1;
        e2 = e2 > 0.f ? e2 : 0.2f * e2;
        e3 = e3 > 0.f ? e3 : 0.2f * e3;
        float w0 = __expf(e0), w1 = __expf(e1), w2 = __expf(e2), w3 = __expf(e3);
        float h0 = h[(size_t)s0 * 64 + lane];
        float h1 = h[(size_t)s1 * 64 + lane];
        float h2 = h[(size_t)s2 * 64 + lane];
        float h3 = h[(size_t)s3 * 64 + lane];
        den += (w0 + w1) + (w2 + w3);
        acc += (w0 * h0 + w1 * h1) + (w2 * h2 + w3 * h3);
    }
    for (; j < end; j++) {
        int s0 = sorted_src[j];
        float e0 = as_[s0] + a_d;
        e0 = e0 > 0.f ? e0 : 0.2f * e0;
        float w0 = __expf(e0);
        den += w0;
        acc += w0 * h[(size_t)s0 * 64 + lane];
    }
    float v = acc / den + bias[lane];
    v = v > 0.f ? v : 0.f;                 // layer-2 output row, in registers only
#pragma unroll
    for (int q = 0; q < 3; q++) {
        float p = v * Wf[lane * 3 + q];
#pragma unroll
        for (int off = 32; off; off >>= 1) p += __shfl_xor(p, off);
        if (lane == 0) out[(size_t)wid * 3 + q] = p + bf[q];
    }
#pragma unroll
    for (int q = 0; q < 7; q++) {
        float p = v * Ws[lane * 7 + q];
#pragma unroll
        for (int off = 32; off; off >>= 1) p += __shfl_xor(p, off);
        if (lane == 0) out[(size_t)N * 3 + (size_t)wid * 7 + q] = p + bs[q];
    }
}

extern "C" void kernel_launch(void* const* d_in, const int* in_sizes, int n_in,
                              void* d_out, int out_size, void* d_ws, size_t ws_size,
                              hipStream_t stream) {
    const float* x      = (const float*)d_in[0];
    const int*   ei     = (const int*)  d_in[1];
    const float* W1     = (const float*)d_in[2];
    const float* a_src1 = (const float*)d_in[3];
    const float* a_dst1 = (const float*)d_in[4];
    const float* b1     = (const float*)d_in[5];
    const float* W2     = (const float*)d_in[6];
    const float* a_src2 = (const float*)d_in[7];
    const float* a_dst2 = (const float*)d_in[8];
    const float* b2     = (const float*)d_in[9];
    const float* Wf     = (const float*)d_in[10];
    const float* bf     = (const float*)d_in[11];
    const float* Ws     = (const float*)d_in[12];
    const float* bs     = (const float*)d_in[13];
    float* out = (float*)d_out;

    const int IN = 256;
    int N = in_sizes[0] / IN;      // 100000
    int E = in_sizes[1] / 2;       // 1600000
    int total = E + N;

    char* ws = (char*)d_ws;
    float* h        = (float*)ws;  ws += (size_t)N * 64 * sizeof(float);
    float* g        = (float*)ws;  ws += (size_t)N * 64 * sizeof(float);
    float* as_      = (float*)ws;  ws += (size_t)N * sizeof(float);
    float* ad_      = (float*)ws;  ws += (size_t)N * sizeof(float);
    int* rowstart   = (int*)ws;    ws += (size_t)(N + 1) * sizeof(int);
    int* cursor     = (int*)ws;    ws += (size_t)N * sizeof(int);   // also deg
    int* sorted_src = (int*)ws;    ws += (size_t)total * sizeof(int);
    int* partials   = (int*)ws;    ws += 1024 * sizeof(int);

    const int* esrc = ei;
    const int* edst = ei + E;

    float inv = 8.0f / (float)N;
    int nblk = (N + 1023) / 1024;
    int gemmGrid = (N + 127) / 128;
    int aggGrid  = (N * 64 + 255) / 256;
    int pcE = (E + 255) / 256;
    int pcT = (total + 255) / 256;

    // ---- build CSR (XCD-region-partitioned atomics/writes) ----
    init_deg<<<(N + 255) / 256, 256, 0, stream>>>(cursor, N);
    count_deg_r<<<2048, 256, 0, stream>>>(edst, cursor, E, inv, pcE);
    scan_pass1<<<nblk, 256, 0, stream>>>(cursor, partials, N);
    scan_pass2<<<1, 256, 0, stream>>>(partials, nblk);
    scan_pass3<<<nblk, 256, 0, stream>>>(cursor, partials, rowstart, N);
    hipMemcpyAsync(cursor, rowstart, (size_t)N * sizeof(int), hipMemcpyDeviceToDevice, stream);
    scatter_r<<<2048, 256, 0, stream>>>(esrc, edst, cursor, sorted_src, E, total, inv, pcT);

    // ---- layer 1 ----
    gemm_alpha<<<gemmGrid, 256, 0, stream>>>(x, W1, a_src1, a_dst1, h, as_, ad_, N, IN);
    aggregate_kernel<<<aggGrid, 256, 0, stream>>>(h, as_, ad_, rowstart, sorted_src, b1, g, N, total);

    // ---- layer 2 (+ fused heads) ----
    gemm_alpha<<<gemmGrid, 256, 0, stream>>>(g, W2, a_src2, a_dst2, h, as_, ad_, N, 64);
    aggregate_heads<<<aggGrid, 256, 0, stream>>>(h, as_, ad_, rowstart, sorted_src, b2,
                                                 Wf, bf, Ws, bs, out, N, total);
}

// Round 5
// 570.209 us; speedup vs baseline: 2.3019x; 1.0389x over previous
//
#include <hip/hip_runtime.h>
#include <hip/hip_fp16.h>

// ================= graph build: CSR by dst, XCD-region-partitioned =================
__global__ __launch_bounds__(256) void count_deg_r(const int* __restrict__ edst,
                                                   int* __restrict__ deg, int E,
                                                   float inv, int per_chunk) {
    int r = blockIdx.x & 7;
    int chunk = blockIdx.x >> 3;
    int base = chunk * per_chunk;
    int end = min(E, base + per_chunk);
    for (int e = base + (int)threadIdx.x; e < end; e += 256) {
        int d = edst[e];
        int reg = (int)((float)d * inv); reg = reg > 7 ? 7 : reg;
        if (reg == r) atomicAdd(&deg[d], 1);
    }
}

__global__ __launch_bounds__(256) void scan_pass1(const int* __restrict__ deg,
                                                  int* __restrict__ partials, int N) {
    __shared__ int sd[256];
    int b = blockIdx.x, t = threadIdx.x;
    int base = b * 1024 + t * 4;
    int s = 0;
#pragma unroll
    for (int k = 0; k < 4; k++) s += (base + k < N) ? deg[base + k] : 0;
    sd[t] = s; __syncthreads();
    for (int off = 1; off < 256; off <<= 1) {
        int v = (t >= off) ? sd[t - off] : 0;
        __syncthreads();
        sd[t] += v;
        __syncthreads();
    }
    if (t == 255) partials[b] = sd[255];
}

__global__ __launch_bounds__(256) void scan_pass2(int* __restrict__ partials, int nblk) {
    __shared__ int sd[256];
    int t = threadIdx.x;
    int v[4]; int s = 0;
#pragma unroll
    for (int k = 0; k < 4; k++) { int i = t * 4 + k; v[k] = (i < nblk) ? partials[i] : 0; s += v[k]; }
    sd[t] = s; __syncthreads();
    for (int off = 1; off < 256; off <<= 1) {
        int x = (t >= off) ? sd[t - off] : 0;
        __syncthreads();
        sd[t] += x;
        __syncthreads();
    }
    int run = sd[t] - s;
#pragma unroll
    for (int k = 0; k < 4; k++) { int i = t * 4 + k; if (i < nblk) partials[i] = run; run += v[k]; }
}

// writes rowstart AND cursor (identical copies) so no memcpy is needed
__global__ __launch_bounds__(256) void scan_pass3(const int* __restrict__ deg,
                                                  const int* __restrict__ partials,
                                                  int* __restrict__ rowstart,
                                                  int* __restrict__ cursor, int N) {
    __shared__ int sd[256];
    int b = blockIdx.x, t = threadIdx.x;
    int base = b * 1024 + t * 4;
    int v[4]; int s = 0;
#pragma unroll
    for (int k = 0; k < 4; k++) { v[k] = (base + k < N) ? deg[base + k] : 0; s += v[k]; }
    sd[t] = s; __syncthreads();
    for (int off = 1; off < 256; off <<= 1) {
        int x = (t >= off) ? sd[t - off] : 0;
        __syncthreads();
        sd[t] += x;
        __syncthreads();
    }
    int run = partials[b] + sd[t] - s;
#pragma unroll
    for (int k = 0; k < 4; k++) {
        if (base + k < N) { rowstart[base + k] = run; cursor[base + k] = run; }
        run += v[k];
    }
}

__global__ __launch_bounds__(256) void scatter_r(const int* __restrict__ esrc,
                                                 const int* __restrict__ edst,
                                                 int* __restrict__ cursor,
                                                 int* __restrict__ sorted_src,
                                                 int E, float inv, int per_chunk) {
    int r = blockIdx.x & 7;
    int chunk = blockIdx.x >> 3;
    int base = chunk * per_chunk;
    int end = min(E, base + per_chunk);
    for (int e = base + (int)threadIdx.x; e < end; e += 256) {
        int s = esrc[e], d = edst[e];
        int reg = (int)((float)d * inv); reg = reg > 7 ? 7 : reg;
        if (reg == r) {
            int pos = atomicAdd(&cursor[d], 1);
            sorted_src[pos] = s;
        }
    }
}

// ====== GEMM + fused alpha: C(fp16)[M,64] = A[M,K]@W[K,64]; as_=C.a_src, ad_=C.a_dst ======
// 128x64 tile, 256 threads, 4x8 micro-tile, BK=32.
__global__ __launch_bounds__(256) void gemm_alpha(const float* __restrict__ A,
                                                  const float* __restrict__ W,
                                                  const float* __restrict__ a_src,
                                                  const float* __restrict__ a_dst,
                                                  __half* __restrict__ C,
                                                  float* __restrict__ as_,
                                                  float* __restrict__ ad_,
                                                  int M, int K) {
    const int BK = 32;
    __shared__ float AsT[BK][132];
    __shared__ float Bs[BK][64];
    int tid = threadIdx.x;
    int tx = tid & 7;
    int ty = tid >> 3;
    int rowBase = blockIdx.x * 128;
    float acc[4][8] = {};

    float asv[8], adv[8];
#pragma unroll
    for (int j = 0; j < 8; j++) { asv[j] = a_src[tx * 8 + j]; adv[j] = a_dst[tx * 8 + j]; }

    for (int k0 = 0; k0 < K; k0 += BK) {
#pragma unroll
        for (int i = 0; i < 4; i++) {
            int fidx = 4 * (tid + i * 256);
            int r = fidx >> 5, c = fidx & 31;
            int gr = rowBase + r;
            float4 v = (gr < M) ? *reinterpret_cast<const float4*>(&A[(size_t)gr * K + k0 + c])
                                : make_float4(0.f, 0.f, 0.f, 0.f);
            AsT[c + 0][r] = v.x;
            AsT[c + 1][r] = v.y;
            AsT[c + 2][r] = v.z;
            AsT[c + 3][r] = v.w;
        }
#pragma unroll
        for (int i = 0; i < 2; i++) {
            int fidx = 4 * (tid + i * 256);
            int r = fidx >> 6, c = fidx & 63;
            *reinterpret_cast<float4*>(&Bs[r][c]) =
                *reinterpret_cast<const float4*>(&W[(size_t)(k0 + r) * 64 + c]);
        }
        __syncthreads();
#pragma unroll 4
        for (int kk = 0; kk < BK; ++kk) {
            float a[4], b[8];
            *reinterpret_cast<float4*>(&a[0]) = *reinterpret_cast<const float4*>(&AsT[kk][ty * 4]);
            *reinterpret_cast<float4*>(&b[0]) = *reinterpret_cast<const float4*>(&Bs[kk][tx * 8]);
            *reinterpret_cast<float4*>(&b[4]) = *reinterpret_cast<const float4*>(&Bs[kk][tx * 8 + 4]);
#pragma unroll
            for (int i = 0; i < 4; i++)
#pragma unroll
                for (int j = 0; j < 8; j++)
                    acc[i][j] += a[i] * b[j];
        }
        __syncthreads();
    }

#pragma unroll
    for (int i = 0; i < 4; i++) {
        int gr = rowBase + ty * 4 + i;
        float s1 = 0.f, s2 = 0.f;
#pragma unroll
        for (int j = 0; j < 8; j++) { s1 += acc[i][j] * asv[j]; s2 += acc[i][j] * adv[j]; }
        s1 += __shfl_xor(s1, 1); s2 += __shfl_xor(s2, 1);
        s1 += __shfl_xor(s1, 2); s2 += __shfl_xor(s2, 2);
        s1 += __shfl_xor(s1, 4); s2 += __shfl_xor(s2, 4);
        if (gr < M) {
            __half hb[8];
#pragma unroll
            for (int j = 0; j < 8; j++) hb[j] = __float2half(acc[i][j]);
            *reinterpret_cast<float4*>(&C[(size_t)gr * 64 + tx * 8]) =
                *reinterpret_cast<const float4*>(&hb[0]);
            if (tx == 0) { as_[gr] = s1; ad_[gr] = s2; }
        }
    }
}

// ================= gather aggregation (fp16 h): one wave per dst node =================
__global__ __launch_bounds__(256) void aggregate_kernel(const __half* __restrict__ h,
                                                        const float* __restrict__ as_,
                                                        const float* __restrict__ ad_,
                                                        const int* __restrict__ rowstart,
                                                        const int* __restrict__ sorted_src,
                                                        const float* __restrict__ bias,
                                                        float* __restrict__ outp,
                                                        int N, int E) {
    int wid = (blockIdx.x * blockDim.x + threadIdx.x) >> 6;
    int lane = threadIdx.x & 63;
    if (wid >= N) return;
    int beg = rowstart[wid];
    int end = (wid + 1 < N) ? rowstart[wid + 1] : E;
    float a_d = ad_[wid];
    // analytic self-loop
    float es = as_[wid] + a_d;
    es = es > 0.f ? es : 0.2f * es;
    float wself = __expf(es);
    float den = wself;
    float acc = wself * __half2float(h[(size_t)wid * 64 + lane]);
    int j = beg;
    for (; j + 3 < end; j += 4) {
        int s0 = sorted_src[j],     s1 = sorted_src[j + 1];
        int s2 = sorted_src[j + 2], s3 = sorted_src[j + 3];
        float e0 = as_[s0] + a_d, e1 = as_[s1] + a_d;
        float e2 = as_[s2] + a_d, e3 = as_[s3] + a_d;
        e0 = e0 > 0.f ? e0 : 0.2f * e0;
        e1 = e1 > 0.f ? e1 : 0.2f * e1;
        e2 = e2 > 0.f ? e2 : 0.2f * e2;
        e3 = e3 > 0.f ? e3 : 0.2f * e3;
        float w0 = __expf(e0), w1 = __expf(e1), w2 = __expf(e2), w3 = __expf(e3);
        float h0 = __half2float(h[(size_t)s0 * 64 + lane]);
        float h1 = __half2float(h[(size_t)s1 * 64 + lane]);
        float h2 = __half2float(h[(size_t)s2 * 64 + lane]);
        float h3 = __half2float(h[(size_t)s3 * 64 + lane]);
        den += (w0 + w1) + (w2 + w3);
        acc += (w0 * h0 + w1 * h1) + (w2 * h2 + w3 * h3);
    }
    for (; j < end; j++) {
        int s0 = sorted_src[j];
        float e0 = as_[s0] + a_d;
        e0 = e0 > 0.f ? e0 : 0.2f * e0;
        float w0 = __expf(e0);
        den += w0;
        acc += w0 * __half2float(h[(size_t)s0 * 64 + lane]);
    }
    float v = acc / den + bias[lane];
    outp[(size_t)wid * 64 + lane] = v > 0.f ? v : 0.f;
}

// ====== layer-2 aggregate with fused heads ======
__global__ __launch_bounds__(256) void aggregate_heads(const __half* __restrict__ h,
                                                       const float* __restrict__ as_,
                                                       const float* __restrict__ ad_,
                                                       const int* __restrict__ rowstart,
                                                       const int* __restrict__ sorted_src,
                                                       const float* __restrict__ bias,
                                                       const float* __restrict__ Wf,
                                                       const float* __restrict__ bf,
                                                       const float* __restrict__ Ws,
                                                       const float* __restrict__ bs,
                                                       float* __restrict__ out,
                                                       int N, int E) {
    int wid = (blockIdx.x * blockDim.x + threadIdx.x) >> 6;
    int lane = threadIdx.x & 63;
    if (wid >= N) return;
    int beg = rowstart[wid];
    int end = (wid + 1 < N) ? rowstart[wid + 1] : E;
    float a_d = ad_[wid];
    float es = as_[wid] + a_d;
    es = es > 0.f ? es : 0.2f * es;
    float wself = __expf(es);
    float den = wself;
    float acc = wself * __half2float(h[(size_t)wid * 64 + lane]);
    int j = beg;
    for (; j + 3 < end; j += 4) {
        int s0 = sorted_src[j],     s1 = sorted_src[j + 1];
        int s2 = sorted_src[j + 2], s3 = sorted_src[j + 3];
        float e0 = as_[s0] + a_d, e1 = as_[s1] + a_d;
        float e2 = as_[s2] + a_d, e3 = as_[s3] + a_d;
        e0 = e0 > 0.f ? e0 : 0.2f * e0;
        e1 = e1 > 0.f ? e1 : 0.2f * e1;
        e2 = e2 > 0.f ? e2 : 0.2f * e2;
        e3 = e3 > 0.f ? e3 : 0.2f * e3;
        float w0 = __expf(e0), w1 = __expf(e1), w2 = __expf(e2), w3 = __expf(e3);
        float h0 = __half2float(h[(size_t)s0 * 64 + lane]);
        float h1 = __half2float(h[(size_t)s1 * 64 + lane]);
        float h2 = __half2float(h[(size_t)s2 * 64 + lane]);
        float h3 = __half2float(h[(size_t)s3 * 64 + lane]);
        den += (w0 + w1) + (w2 + w3);
        acc += (w0 * h0 + w1 * h1) + (w2 * h2 + w3 * h3);
    }
    for (; j < end; j++) {
        int s0 = sorted_src[j];
        float e0 = as_[s0] + a_d;
        e0 = e0 > 0.f ? e0 : 0.2f * e0;
        float w0 = __expf(e0);
        den += w0;
        acc += w0 * __half2float(h[(size_t)s0 * 64 + lane]);
    }
    float v = acc / den + bias[lane];
    v = v > 0.f ? v : 0.f;                 // layer-2 output row stays in registers
#pragma unroll
    for (int q = 0; q < 3; q++) {
        float p = v * Wf[lane * 3 + q];
#pragma unroll
        for (int off = 32; off; off >>= 1) p += __shfl_xor(p, off);
        if (lane == 0) out[(size_t)wid * 3 + q] = p + bf[q];
    }
#pragma unroll
    for (int q = 0; q < 7; q++) {
        float p = v * Ws[lane * 7 + q];
#pragma unroll
        for (int off = 32; off; off >>= 1) p += __shfl_xor(p, off);
        if (lane == 0) out[(size_t)N * 3 + (size_t)wid * 7 + q] = p + bs[q];
    }
}

extern "C" void kernel_launch(void* const* d_in, const int* in_sizes, int n_in,
                              void* d_out, int out_size, void* d_ws, size_t ws_size,
                              hipStream_t stream) {
    const float* x      = (const float*)d_in[0];
    const int*   ei     = (const int*)  d_in[1];
    const float* W1     = (const float*)d_in[2];
    const float* a_src1 = (const float*)d_in[3];
    const float* a_dst1 = (const float*)d_in[4];
    const float* b1     = (const float*)d_in[5];
    const float* W2     = (const float*)d_in[6];
    const float* a_src2 = (const float*)d_in[7];
    const float* a_dst2 = (const float*)d_in[8];
    const float* b2     = (const float*)d_in[9];
    const float* Wf     = (const float*)d_in[10];
    const float* bf     = (const float*)d_in[11];
    const float* Ws     = (const float*)d_in[12];
    const float* bs     = (const float*)d_in[13];
    float* out = (float*)d_out;

    const int IN = 256;
    int N = in_sizes[0] / IN;      // 100000
    int E = in_sizes[1] / 2;       // 1600000

    char* ws = (char*)d_ws;
    __half* h       = (__half*)ws; ws += (size_t)N * 64 * sizeof(__half);
    float* g        = (float*)ws;  ws += (size_t)N * 64 * sizeof(float);
    float* as_      = (float*)ws;  ws += (size_t)N * sizeof(float);
    float* ad_      = (float*)ws;  ws += (size_t)N * sizeof(float);
    int* rowstart   = (int*)ws;    ws += (size_t)(N + 1) * sizeof(int);
    int* cursor     = (int*)ws;    ws += (size_t)N * sizeof(int);   // also deg
    int* sorted_src = (int*)ws;    ws += (size_t)E * sizeof(int);
    int* partials   = (int*)ws;    ws += 1024 * sizeof(int);

    const int* esrc = ei;
    const int* edst = ei + E;

    float inv = 8.0f / (float)N;
    int nblk = (N + 1023) / 1024;
    int gemmGrid = (N + 127) / 128;
    int aggGrid  = (N * 64 + 255) / 256;
    int pcE = (E + 255) / 256;

    // ---- build CSR over real edges (self-loops handled analytically) ----
    hipMemsetAsync(cursor, 0, (size_t)N * sizeof(int), stream);
    count_deg_r<<<2048, 256, 0, stream>>>(edst, cursor, E, inv, pcE);
    scan_pass1<<<nblk, 256, 0, stream>>>(cursor, partials, N);
    scan_pass2<<<1, 256, 0, stream>>>(partials, nblk);
    scan_pass3<<<nblk, 256, 0, stream>>>(cursor, partials, rowstart, cursor, N);
    scatter_r<<<2048, 256, 0, stream>>>(esrc, edst, cursor, sorted_src, E, inv, pcE);

    // ---- layer 1 ----
    gemm_alpha<<<gemmGrid, 256, 0, stream>>>(x, W1, a_src1, a_dst1, h, as_, ad_, N, IN);
    aggregate_kernel<<<aggGrid, 256, 0, stream>>>(h, as_, ad_, rowstart, sorted_src, b1, g, N, E);

    // ---- layer 2 (+ fused heads) ----
    gemm_alpha<<<gemmGrid, 256, 0, stream>>>(g, W2, a_src2, a_dst2, h, as_, ad_, N, 64);
    aggregate_heads<<<aggGrid, 256, 0, stream>>>(h, as_, ad_, rowstart, sorted_src, b2,
                                                 Wf, bf, Ws, bs, out, N, E);
}

// Round 7
// 547.023 us; speedup vs baseline: 2.3995x; 1.0424x over previous
//
#include <hip/hip_runtime.h>
#include <hip/hip_fp16.h>

// ================= graph build: CSR by dst, XCD-region-partitioned =================
__global__ __launch_bounds__(256) void count_deg_r(const int* __restrict__ edst,
                                                   int* __restrict__ deg, int E,
                                                   float inv, int per_chunk) {
    int r = blockIdx.x & 7;
    int chunk = blockIdx.x >> 3;
    int base = chunk * per_chunk;
    int end = min(E, base + per_chunk);
    for (int e = base + (int)threadIdx.x; e < end; e += 256) {
        int d = edst[e];
        int reg = (int)((float)d * inv); reg = reg > 7 ? 7 : reg;
        if (reg == r) atomicAdd(&deg[d], 1);
    }
}

__global__ __launch_bounds__(256) void scan_pass1(const int* __restrict__ deg,
                                                  int* __restrict__ partials, int N) {
    __shared__ int sd[256];
    int b = blockIdx.x, t = threadIdx.x;
    int base = b * 1024 + t * 4;
    int s = 0;
#pragma unroll
    for (int k = 0; k < 4; k++) s += (base + k < N) ? deg[base + k] : 0;
    sd[t] = s; __syncthreads();
    for (int off = 1; off < 256; off <<= 1) {
        int v = (t >= off) ? sd[t - off] : 0;
        __syncthreads();
        sd[t] += v;
        __syncthreads();
    }
    if (t == 255) partials[b] = sd[255];
}

__global__ __launch_bounds__(256) void scan_pass2(int* __restrict__ partials, int nblk) {
    __shared__ int sd[256];
    int t = threadIdx.x;
    int v[4]; int s = 0;
#pragma unroll
    for (int k = 0; k < 4; k++) { int i = t * 4 + k; v[k] = (i < nblk) ? partials[i] : 0; s += v[k]; }
    sd[t] = s; __syncthreads();
    for (int off = 1; off < 256; off <<= 1) {
        int x = (t >= off) ? sd[t - off] : 0;
        __syncthreads();
        sd[t] += x;
        __syncthreads();
    }
    int run = sd[t] - s;
#pragma unroll
    for (int k = 0; k < 4; k++) { int i = t * 4 + k; if (i < nblk) partials[i] = run; run += v[k]; }
}

// writes rowstart AND cursor (identical copies) so no memcpy is needed
__global__ __launch_bounds__(256) void scan_pass3(const int* __restrict__ deg,
                                                  const int* __restrict__ partials,
                                                  int* __restrict__ rowstart,
                                                  int* __restrict__ cursor, int N) {
    __shared__ int sd[256];
    int b = blockIdx.x, t = threadIdx.x;
    int base = b * 1024 + t * 4;
    int v[4]; int s = 0;
#pragma unroll
    for (int k = 0; k < 4; k++) { v[k] = (base + k < N) ? deg[base + k] : 0; s += v[k]; }
    sd[t] = s; __syncthreads();
    for (int off = 1; off < 256; off <<= 1) {
        int x = (t >= off) ? sd[t - off] : 0;
        __syncthreads();
        sd[t] += x;
        __syncthreads();
    }
    int run = partials[b] + sd[t] - s;
#pragma unroll
    for (int k = 0; k < 4; k++) {
        if (base + k < N) { rowstart[base + k] = run; cursor[base + k] = run; }
        run += v[k];
    }
}

__global__ __launch_bounds__(256) void scatter_r(const int* __restrict__ esrc,
                                                 const int* __restrict__ edst,
                                                 int* __restrict__ cursor,
                                                 int* __restrict__ sorted_src,
                                                 int E, float inv, int per_chunk) {
    int r = blockIdx.x & 7;
    int chunk = blockIdx.x >> 3;
    int base = chunk * per_chunk;
    int end = min(E, base + per_chunk);
    for (int e = base + (int)threadIdx.x; e < end; e += 256) {
        int s = esrc[e], d = edst[e];
        int reg = (int)((float)d * inv); reg = reg > 7 ? 7 : reg;
        if (reg == r) {
            int pos = atomicAdd(&cursor[d], 1);
            sorted_src[pos] = s;
        }
    }
}

// ====== GEMM + fused alpha: C(fp16)[M,64] = A[M,K]@W[K,64]; as_=C.a_src, ad_=C.a_dst ======
__global__ __launch_bounds__(256) void gemm_alpha(const float* __restrict__ A,
                                                  const float* __restrict__ W,
                                                  const float* __restrict__ a_src,
                                                  const float* __restrict__ a_dst,
                                                  __half* __restrict__ C,
                                                  float* __restrict__ as_,
                                                  float* __restrict__ ad_,
                                                  int M, int K) {
    const int BK = 32;
    __shared__ float AsT[BK][132];
    __shared__ float Bs[BK][64];
    int tid = threadIdx.x;
    int tx = tid & 7;
    int ty = tid >> 3;
    int rowBase = blockIdx.x * 128;
    float acc[4][8] = {};

    float asv[8], adv[8];
#pragma unroll
    for (int j = 0; j < 8; j++) { asv[j] = a_src[tx * 8 + j]; adv[j] = a_dst[tx * 8 + j]; }

    for (int k0 = 0; k0 < K; k0 += BK) {
#pragma unroll
        for (int i = 0; i < 4; i++) {
            int fidx = 4 * (tid + i * 256);
            int r = fidx >> 5, c = fidx & 31;
            int gr = rowBase + r;
            float4 v = (gr < M) ? *reinterpret_cast<const float4*>(&A[(size_t)gr * K + k0 + c])
                                : make_float4(0.f, 0.f, 0.f, 0.f);
            AsT[c + 0][r] = v.x;
            AsT[c + 1][r] = v.y;
            AsT[c + 2][r] = v.z;
            AsT[c + 3][r] = v.w;
        }
#pragma unroll
        for (int i = 0; i < 2; i++) {
            int fidx = 4 * (tid + i * 256);
            int r = fidx >> 6, c = fidx & 63;
            *reinterpret_cast<float4*>(&Bs[r][c]) =
                *reinterpret_cast<const float4*>(&W[(size_t)(k0 + r) * 64 + c]);
        }
        __syncthreads();
#pragma unroll 4
        for (int kk = 0; kk < BK; ++kk) {
            float a[4], b[8];
            *reinterpret_cast<float4*>(&a[0]) = *reinterpret_cast<const float4*>(&AsT[kk][ty * 4]);
            *reinterpret_cast<float4*>(&b[0]) = *reinterpret_cast<const float4*>(&Bs[kk][tx * 8]);
            *reinterpret_cast<float4*>(&b[4]) = *reinterpret_cast<const float4*>(&Bs[kk][tx * 8 + 4]);
#pragma unroll
            for (int i = 0; i < 4; i++)
#pragma unroll
                for (int j = 0; j < 8; j++)
                    acc[i][j] += a[i] * b[j];
        }
        __syncthreads();
    }

#pragma unroll
    for (int i = 0; i < 4; i++) {
        int gr = rowBase + ty * 4 + i;
        float s1 = 0.f, s2 = 0.f;
#pragma unroll
        for (int j = 0; j < 8; j++) { s1 += acc[i][j] * asv[j]; s2 += acc[i][j] * adv[j]; }
        s1 += __shfl_xor(s1, 1); s2 += __shfl_xor(s2, 1);
        s1 += __shfl_xor(s1, 2); s2 += __shfl_xor(s2, 2);
        s1 += __shfl_xor(s1, 4); s2 += __shfl_xor(s2, 4);
        if (gr < M) {
            __half hb[8];
#pragma unroll
            for (int j = 0; j < 8; j++) hb[j] = __float2half(acc[i][j]);
            *reinterpret_cast<float4*>(&C[(size_t)gr * 64 + tx * 8]) =
                *reinterpret_cast<const float4*>(&hb[0]);
            if (tx == 0) { as_[gr] = s1; ad_[gr] = s2; }
        }
    }
}

// ===== aggregate core: lane-parallel weights + shuffle-broadcast gather =====
// Returns normalized+biased+relu'd channel value for this (node, lane).
__device__ __forceinline__ float agg_node(const __half* __restrict__ h,
                                          const float* __restrict__ as_,
                                          const float* __restrict__ ad_,
                                          const int* __restrict__ rowstart,
                                          const int* __restrict__ sorted_src,
                                          const float* __restrict__ bias,
                                          int wid, int lane, int N, int E) {
    int beg = rowstart[wid];
    int end = (wid + 1 < N) ? rowstart[wid + 1] : E;
    float a_d = ad_[wid];
    // analytic self-loop (uniform across lanes)
    float es = as_[wid] + a_d;
    es = es > 0.f ? es : 0.2f * es;
    float wself = __expf(es);
    const __half* hl = h + lane;                 // per-lane channel base
    float acc = wself * __half2float(hl[(unsigned)wid * 64u]);
    float denp = 0.f;                            // per-lane partial of denominator

    for (int c = beg; c < end; c += 64) {
        int idx = c + lane;
        int sl = 0; float wl = 0.f;
        if (idx < end) {                         // lane j computes weight of edge c+j ONCE
            sl = sorted_src[idx];
            float e = as_[sl] + a_d;
            e = e > 0.f ? e : 0.2f * e;
            wl = __expf(e);
        }
        denp += wl;
        int m = end - c; m = m > 64 ? 64 : m;
        int j = 0;
        for (; j + 3 < m; j += 4) {              // broadcast via shuffles (LDS pipe)
            int s0 = __shfl(sl, j),     s1 = __shfl(sl, j + 1);
            int s2 = __shfl(sl, j + 2), s3 = __shfl(sl, j + 3);
            float w0 = __shfl(wl, j),     w1 = __shfl(wl, j + 1);
            float w2 = __shfl(wl, j + 2), w3 = __shfl(wl, j + 3);
            float h0 = __half2float(hl[(unsigned)s0 * 64u]);
            float h1 = __half2float(hl[(unsigned)s1 * 64u]);
            float h2 = __half2float(hl[(unsigned)s2 * 64u]);
            float h3 = __half2float(hl[(unsigned)s3 * 64u]);
            acc += (w0 * h0 + w1 * h1) + (w2 * h2 + w3 * h3);
        }
        for (; j < m; j++) {
            int s0 = __shfl(sl, j);
            float w0 = __shfl(wl, j);
            acc += w0 * __half2float(hl[(unsigned)s0 * 64u]);
        }
    }
    // reduce denominator partials across all 64 lanes (result in every lane)
#pragma unroll
    for (int off = 32; off; off >>= 1) denp += __shfl_xor(denp, off);
    float den = denp + wself;
    float v = acc / den + bias[lane];
    return v > 0.f ? v : 0.f;
}

__global__ __launch_bounds__(256) void aggregate_kernel(const __half* __restrict__ h,
                                                        const float* __restrict__ as_,
                                                        const float* __restrict__ ad_,
                                                        const int* __restrict__ rowstart,
                                                        const int* __restrict__ sorted_src,
                                                        const float* __restrict__ bias,
                                                        float* __restrict__ outp,
                                                        int N, int E) {
    int wid = (blockIdx.x * blockDim.x + threadIdx.x) >> 6;
    int lane = threadIdx.x & 63;
    if (wid >= N) return;
    float v = agg_node(h, as_, ad_, rowstart, sorted_src, bias, wid, lane, N, E);
    outp[(size_t)wid * 64 + lane] = v;
}

__global__ __launch_bounds__(256) void aggregate_heads(const __half* __restrict__ h,
                                                       const float* __restrict__ as_,
                                                       const float* __restrict__ ad_,
                                                       const int* __restrict__ rowstart,
                                                       const int* __restrict__ sorted_src,
                                                       const float* __restrict__ bias,
                                                       const float* __restrict__ Wf,
                                                       const float* __restrict__ bf,
                                                       const float* __restrict__ Ws,
                                                       const float* __restrict__ bs,
                                                       float* __restrict__ out,
                                                       int N, int E) {
    int wid = (blockIdx.x * blockDim.x + threadIdx.x) >> 6;
    int lane = threadIdx.x & 63;
    if (wid >= N) return;
    float v = agg_node(h, as_, ad_, rowstart, sorted_src, bias, wid, lane, N, E);
#pragma unroll
    for (int q = 0; q < 3; q++) {
        float p = v * Wf[lane * 3 + q];
#pragma unroll
        for (int off = 32; off; off >>= 1) p += __shfl_xor(p, off);
        if (lane == 0) out[(size_t)wid * 3 + q] = p + bf[q];
    }
#pragma unroll
    for (int q = 0; q < 7; q++) {
        float p = v * Ws[lane * 7 + q];
#pragma unroll
        for (int off = 32; off; off >>= 1) p += __shfl_xor(p, off);
        if (lane == 0) out[(size_t)N * 3 + (size_t)wid * 7 + q] = p + bs[q];
    }
}

extern "C" void kernel_launch(void* const* d_in, const int* in_sizes, int n_in,
                              void* d_out, int out_size, void* d_ws, size_t ws_size,
                              hipStream_t stream) {
    const float* x      = (const float*)d_in[0];
    const int*   ei     = (const int*)  d_in[1];
    const float* W1     = (const float*)d_in[2];
    const float* a_src1 = (const float*)d_in[3];
    const float* a_dst1 = (const float*)d_in[4];
    const float* b1     = (const float*)d_in[5];
    const float* W2     = (const float*)d_in[6];
    const float* a_src2 = (const float*)d_in[7];
    const float* a_dst2 = (const float*)d_in[8];
    const float* b2     = (const float*)d_in[9];
    const float* Wf     = (const float*)d_in[10];
    const float* bf     = (const float*)d_in[11];
    const float* Ws     = (const float*)d_in[12];
    const float* bs     = (const float*)d_in[13];
    float* out = (float*)d_out;

    const int IN = 256;
    int N = in_sizes[0] / IN;      // 100000
    int E = in_sizes[1] / 2;       // 1600000

    char* ws = (char*)d_ws;
    __half* h       = (__half*)ws; ws += (size_t)N * 64 * sizeof(__half);
    float* g        = (float*)ws;  ws += (size_t)N * 64 * sizeof(float);
    float* as_      = (float*)ws;  ws += (size_t)N * sizeof(float);
    float* ad_      = (float*)ws;  ws += (size_t)N * sizeof(float);
    int* rowstart   = (int*)ws;    ws += (size_t)(N + 1) * sizeof(int);
    int* cursor     = (int*)ws;    ws += (size_t)N * sizeof(int);   // also deg
    int* sorted_src = (int*)ws;    ws += (size_t)E * sizeof(int);
    int* partials   = (int*)ws;    ws += 1024 * sizeof(int);

    const int* esrc = ei;
    const int* edst = ei + E;

    float inv = 8.0f / (float)N;
    int nblk = (N + 1023) / 1024;
    int gemmGrid = (N + 127) / 128;
    int aggGrid  = (N * 64 + 255) / 256;
    int pcE = (E + 255) / 256;

    // ---- build CSR over real edges (self-loops handled analytically) ----
    hipMemsetAsync(cursor, 0, (size_t)N * sizeof(int), stream);
    count_deg_r<<<2048, 256, 0, stream>>>(edst, cursor, E, inv, pcE);
    scan_pass1<<<nblk, 256, 0, stream>>>(cursor, partials, N);
    scan_pass2<<<1, 256, 0, stream>>>(partials, nblk);
    scan_pass3<<<nblk, 256, 0, stream>>>(cursor, partials, rowstart, cursor, N);
    scatter_r<<<2048, 256, 0, stream>>>(esrc, edst, cursor, sorted_src, E, inv, pcE);

    // ---- layer 1 ----
    gemm_alpha<<<gemmGrid, 256, 0, stream>>>(x, W1, a_src1, a_dst1, h, as_, ad_, N, IN);
    aggregate_kernel<<<aggGrid, 256, 0, stream>>>(h, as_, ad_, rowstart, sorted_src, b1, g, N, E);

    // ---- layer 2 (+ fused heads) ----
    gemm_alpha<<<gemmGrid, 256, 0, stream>>>(g, W2, a_src2, a_dst2, h, as_, ad_, N, 64);
    aggregate_heads<<<aggGrid, 256, 0, stream>>>(h, as_, ad_, rowstart, sorted_src, b2,
                                                 Wf, bf, Ws, bs, out, N, E);
}